// Round 1
// baseline (507.492 us; speedup 1.0000x reference)
//
#include <hip/hip_runtime.h>
#include <hip/hip_bf16.h>
#include <cstdint>
#include <cstddef>

// Problem constants (from reference)
#define BB 2
#define QQ 2048
#define KK 2048
#define HH 16
#define DD 64
#define DVV 64
#define NEG_INF_F (-1e9f)

static constexpr size_t CTX_ELEMS = (size_t)BB * QQ * HH * DVV;  // 4,194,304

typedef __bf16 bf16x8 __attribute__((ext_vector_type(8)));
typedef __bf16 bf16x4 __attribute__((ext_vector_type(4)));
typedef float  f32x4  __attribute__((ext_vector_type(4)));

// ---------------------------------------------------------------------------
// Kernel 1: S[b,h,q,k] = (Q.K^T)/8 + bias, masked to -1e9 for k >= valid_len.
// 64x64 tile per 256-thread wg; bf16x2-split (3-term) MFMA for fp32 accuracy.
// Wave w owns q-rows [16w,16w+16), all 64 k-cols.
// ---------------------------------------------------------------------------
__global__ __launch_bounds__(256)
void k1_scores(const float* __restrict__ qs, const float* __restrict__ ks,
               const float* __restrict__ bias, const int* __restrict__ vlen,
               float* __restrict__ Sout) {
  const int id = blockIdx.x;
  const int kt = id & 31;
  const int qt = (id >> 5) & 31;
  const int bh = id >> 10;
  const int h  = bh & 15;
  const int b  = bh >> 4;
  const int t  = threadIdx.x;
  const int vl = vlen[b];

  // Fast path: whole k-tile masked -> write -1e9, no compute.
  if (kt * 64 >= vl) {
    const int row = t >> 2;
    const int c0  = (t & 3) << 4;
    const int q   = qt * 64 + row;
    float* dst = Sout + ((size_t)(b * HH + h) * QQ + q) * KK + (size_t)kt * 64 + c0;
    const float4 neg = make_float4(NEG_INF_F, NEG_INF_F, NEG_INF_F, NEG_INF_F);
#pragma unroll
    for (int i = 0; i < 4; ++i) ((float4*)dst)[i] = neg;
    return;
  }

  // LDS tiles: hi/lo bf16 split of Q-tile and K-tile. Pad to 72 (144B stride:
  // 16B-aligned for b128 frag reads, banks spread).
  __shared__ __bf16 Qh_s[64][72];
  __shared__ __bf16 Ql_s[64][72];
  __shared__ __bf16 Kh_s[64][72];
  __shared__ __bf16 Kl_s[64][72];

  {
    const int row = t >> 2;
    const int c0  = (t & 3) << 4;
    const float* qsrc = qs + ((size_t)(b * QQ + qt * 64 + row) * HH + h) * DD + c0;
    const float* ksrc = ks + ((size_t)(b * KK + kt * 64 + row) * HH + h) * DD + c0;
#pragma unroll
    for (int i = 0; i < 4; ++i) {
      const float4 fq = ((const float4*)qsrc)[i];
      const float4 fk = ((const float4*)ksrc)[i];
      float aq[4] = {fq.x, fq.y, fq.z, fq.w};
      float ak[4] = {fk.x, fk.y, fk.z, fk.w};
#pragma unroll
      for (int j = 0; j < 4; ++j) {
        const int c = c0 + i * 4 + j;
        const __bf16 qh = (__bf16)aq[j];
        Qh_s[row][c] = qh;
        Ql_s[row][c] = (__bf16)(aq[j] - (float)qh);
        const __bf16 kh = (__bf16)ak[j];
        Kh_s[row][c] = kh;
        Kl_s[row][c] = (__bf16)(ak[j] - (float)kh);
      }
    }
  }
  __syncthreads();

  const int w    = t >> 6;          // wave 0..3
  const int l    = t & 63;          // lane
  const int fr   = l & 15;          // frag row/col index
  const int koff = (l >> 4) << 3;   // 0,8,16,24
  const int arow = (w << 4) + fr;   // q-row in tile for A-frag

  // A-fragments (Q), shared across the 4 k-col frags.
  bf16x8 aH[2], aL[2];
  aH[0] = *(const bf16x8*)&Qh_s[arow][koff];
  aH[1] = *(const bf16x8*)&Qh_s[arow][32 + koff];
  aL[0] = *(const bf16x8*)&Ql_s[arow][koff];
  aL[1] = *(const bf16x8*)&Ql_s[arow][32 + koff];

  const int qrow0 = qt * 64 + (w << 4) + ((l >> 4) << 2);  // C/D: row=(l>>4)*4+reg

#pragma unroll
  for (int c = 0; c < 4; ++c) {
    f32x4 acc = {0.f, 0.f, 0.f, 0.f};
    const int brow = (c << 4) + fr;  // k-row in tile for B-frag
#pragma unroll
    for (int kk = 0; kk < 2; ++kk) {
      const bf16x8 bH = *(const bf16x8*)&Kh_s[brow][kk * 32 + koff];
      const bf16x8 bL = *(const bf16x8*)&Kl_s[brow][kk * 32 + koff];
      acc = __builtin_amdgcn_mfma_f32_16x16x32_bf16(aL[kk], bH, acc, 0, 0, 0);
      acc = __builtin_amdgcn_mfma_f32_16x16x32_bf16(aH[kk], bL, acc, 0, 0, 0);
      acc = __builtin_amdgcn_mfma_f32_16x16x32_bf16(aH[kk], bH, acc, 0, 0, 0);
    }
    const int col = kt * 64 + (c << 4) + fr;  // C/D: col = lane&15
    const bool masked = (col >= vl);
    const size_t obase = ((size_t)(b * HH + h) * QQ + qrow0) * KK + col;
#pragma unroll
    for (int r = 0; r < 4; ++r) {
      float s = acc[r] * 0.125f + bias[(size_t)(qrow0 + r) * KK + col];
      if (masked) s = NEG_INF_F;
      Sout[obase + (size_t)r * KK] = s;
    }
  }
}

// ---------------------------------------------------------------------------
// Kernel 2: per-wg (b, h, 32 q-rows):
//   A: row max over S; B: l = sum exp(s-m); C: attn = exp(s-m)/l written
//   in place, PV accumulated via bf16 MFMA (P, V staged in LDS).
// ---------------------------------------------------------------------------
__global__ __launch_bounds__(256)
void k2_softmax_pv(const float* __restrict__ vs, const int* __restrict__ vlen,
                   float* __restrict__ dout) {
  float* ctx   = dout;
  float* Sattn = dout + CTX_ELEMS;

  __shared__ float mrow[32];
  __shared__ float invl[32];
  __shared__ __bf16 Pt[32][72];   // probs tile (bf16), 144B stride
  __shared__ __bf16 Vt[64][68];   // V tile (bf16), 136B stride

  const int id = blockIdx.x;
  const int qt = id & 63;
  const int bh = id >> 6;
  const int h  = bh & 15;
  const int b  = bh >> 4;
  const int t  = threadIdx.x;
  const int vl = vlen[b];

  const int row = t >> 3;        // 0..31 : q-row owned for S scan
  const int jc  = t & 7;
  const int c0  = jc << 3;       // 8-col chunk base

  float* Srow = Sattn + ((size_t)(b * HH + h) * QQ + qt * 32 + row) * KK;

  // ---- phase A: row max (only over potentially-valid cols) ----
  float m = -3e38f;
  for (int k0 = c0; k0 < vl; k0 += 64) {
    const float4 s0 = *(const float4*)(Srow + k0);
    const float4 s1 = *(const float4*)(Srow + k0 + 4);
    m = fmaxf(m, fmaxf(fmaxf(s0.x, s0.y), fmaxf(s0.z, s0.w)));
    m = fmaxf(m, fmaxf(fmaxf(s1.x, s1.y), fmaxf(s1.z, s1.w)));
  }
#pragma unroll
  for (int off = 1; off < 8; off <<= 1) m = fmaxf(m, __shfl_xor(m, off));
  if (jc == 0) mrow[row] = m;
  __syncthreads();
  m = mrow[row];

  // ---- phase B: sum of exp ----
  float lsum = 0.f;
  for (int k0 = c0; k0 < vl; k0 += 64) {
    const float4 s0 = *(const float4*)(Srow + k0);
    const float4 s1 = *(const float4*)(Srow + k0 + 4);
    lsum += __expf(s0.x - m) + __expf(s0.y - m) + __expf(s0.z - m) + __expf(s0.w - m);
    lsum += __expf(s1.x - m) + __expf(s1.y - m) + __expf(s1.z - m) + __expf(s1.w - m);
  }
#pragma unroll
  for (int off = 1; off < 8; off <<= 1) lsum += __shfl_xor(lsum, off);
  if (jc == 0) invl[row] = 1.f / lsum;
  __syncthreads();
  const float il = invl[row];

  // ---- phase C: normalize+write attn, PV MFMA ----
  const int w    = t >> 6;
  const int l    = t & 63;
  const int fr   = l & 15;
  const int koff = (l >> 4) << 3;
  const int vrow = t >> 2;          // 0..63 : V stage row
  const int dvc  = (t & 3) << 4;    // V stage 16-col chunk

  f32x4 acc0 = {0.f, 0.f, 0.f, 0.f};  // rows 0..15 of q-slice
  f32x4 acc1 = {0.f, 0.f, 0.f, 0.f};  // rows 16..31

  for (int k0 = 0; k0 < KK; k0 += 64) {
    if (k0 >= vl) {
      // fully masked tile: attn = 0, no staging / MFMA / barriers
      const float4 z = make_float4(0.f, 0.f, 0.f, 0.f);
      *(float4*)(Srow + k0 + c0)     = z;
      *(float4*)(Srow + k0 + c0 + 4) = z;
      continue;
    }
    // probabilities for this thread's 8 elems
    const float4 s0 = *(const float4*)(Srow + k0 + c0);
    const float4 s1 = *(const float4*)(Srow + k0 + c0 + 4);
    float p[8];
    p[0] = __expf(s0.x - m) * il; p[1] = __expf(s0.y - m) * il;
    p[2] = __expf(s0.z - m) * il; p[3] = __expf(s0.w - m) * il;
    p[4] = __expf(s1.x - m) * il; p[5] = __expf(s1.y - m) * il;
    p[6] = __expf(s1.z - m) * il; p[7] = __expf(s1.w - m) * il;
    // write normalized attention in place
    *(float4*)(Srow + k0 + c0)     = make_float4(p[0], p[1], p[2], p[3]);
    *(float4*)(Srow + k0 + c0 + 4) = make_float4(p[4], p[5], p[6], p[7]);
    // stage P (bf16) into LDS
    bf16x8 pv;
#pragma unroll
    for (int i = 0; i < 8; ++i) pv[i] = (__bf16)p[i];
    *(bf16x8*)&Pt[row][c0] = pv;
    // stage V tile (bf16) into LDS
    {
      const float* vsrc = vs + ((size_t)(b * KK + k0 + vrow) * HH + h) * DVV + dvc;
#pragma unroll
      for (int i = 0; i < 4; ++i) {
        const float4 fv = ((const float4*)vsrc)[i];
        bf16x4 bv;
        bv[0] = (__bf16)fv.x; bv[1] = (__bf16)fv.y;
        bv[2] = (__bf16)fv.z; bv[3] = (__bf16)fv.w;
        *(bf16x4*)&Vt[vrow][dvc + i * 4] = bv;
      }
    }
    __syncthreads();

    // MFMA: wave w owns dv cols [16w,16w+16); both 16-row tiles.
#pragma unroll
    for (int kk = 0; kk < 2; ++kk) {
      bf16x8 bf;
#pragma unroll
      for (int e = 0; e < 8; ++e) bf[e] = Vt[kk * 32 + koff + e][(w << 4) + fr];
      const bf16x8 a0 = *(const bf16x8*)&Pt[fr][kk * 32 + koff];
      const bf16x8 a1 = *(const bf16x8*)&Pt[16 + fr][kk * 32 + koff];
      acc0 = __builtin_amdgcn_mfma_f32_16x16x32_bf16(a0, bf, acc0, 0, 0, 0);
      acc1 = __builtin_amdgcn_mfma_f32_16x16x32_bf16(a1, bf, acc1, 0, 0, 0);
    }
    __syncthreads();
  }

  // write ctx: C/D col = lane&15 (dv), row = (l>>4)*4+reg (q)
  const int r0 = (l >> 4) << 2;
  const int dv = (w << 4) + fr;
#pragma unroll
  for (int r = 0; r < 4; ++r) {
    const size_t o = ((size_t)(b * QQ + qt * 32 + r0 + r) * HH + h) * DVV + dv;
    ctx[o] = acc0[r];
    ctx[o + (size_t)16 * HH * DVV] = acc1[r];
  }
}

// ---------------------------------------------------------------------------
extern "C" void kernel_launch(void* const* d_in, const int* in_sizes, int n_in,
                              void* d_out, int out_size, void* d_ws, size_t ws_size,
                              hipStream_t stream) {
  (void)in_sizes; (void)n_in; (void)d_ws; (void)ws_size; (void)out_size;
  const float* qs   = (const float*)d_in[0];
  const float* ks   = (const float*)d_in[1];
  const float* vs   = (const float*)d_in[2];
  const float* bias = (const float*)d_in[3];
  const int*   vlen = (const int*)d_in[4];
  float* out = (float*)d_out;

  // K1: scores into the attn region of d_out
  k1_scores<<<dim3(BB * HH * 32 * 32), dim3(256), 0, stream>>>(
      qs, ks, bias, vlen, out + CTX_ELEMS);
  // K2: softmax (in-place normalize) + PV
  k2_softmax_pv<<<dim3(BB * HH * (QQ / 32)), dim3(256), 0, stream>>>(
      vs, vlen, out);
}

// Round 2
// 459.444 us; speedup vs baseline: 1.1046x; 1.1046x over previous
//
#include <hip/hip_runtime.h>
#include <cstdint>
#include <cstddef>

#define BB 2
#define QQ 2048
#define KK_ 2048
#define HH 16
#define DD 64
#define DVV 64
#define NEG_INF_F (-1e9f)

static constexpr size_t CTX_ELEMS = (size_t)BB * QQ * HH * DVV;  // 4,194,304

typedef _Float16 f16x8 __attribute__((ext_vector_type(8)));
typedef _Float16 f16x2 __attribute__((ext_vector_type(2)));
typedef float    f32x4 __attribute__((ext_vector_type(4)));

// Fused attention: one wg = (b, h, 128 q-rows), 512 threads (8 waves), each
// wave owns 16 q-rows. Pass 1: QK^T (fp16 MFMA) -> running (m, l) per row.
// Pass 2: recompute QK^T, p = exp(s-m)/l, write attn, PV MFMA accumulate.
__global__ __launch_bounds__(512)
void fused_attn(const float* __restrict__ qs, const float* __restrict__ ks,
                const float* __restrict__ vs, const float* __restrict__ bias,
                const int* __restrict__ vlen, float* __restrict__ dout) {
  float* ctx  = dout;
  float* attn = dout + CTX_ELEMS;

  // XCD-chunked swizzle: XCD x gets q-tiles {2x,2x+1} x all 32 bh
  // -> bias slice (2 MB) L2-resident per XCD.
  const int x   = blockIdx.x;            // 0..511
  const int xcd = x & 7;
  const int j   = x >> 3;                // 0..63
  const int qt  = xcd * 2 + (j & 1);     // 0..15
  const int bh  = j >> 1;                // 0..31
  const int h   = bh & 15;
  const int b   = bh >> 4;
  const int vl  = vlen[b];
  const int ntv = (vl + 63) >> 6;        // valid 64-wide k-tiles (1..32)

  const int t  = threadIdx.x;
  const int w  = t >> 6;                 // wave 0..7
  const int l  = t & 63;
  const int fr = l & 15;
  const int g  = l >> 4;

  __shared__ _Float16 Kl[64][72];        // K tile   [k][d]   (144B stride, 16B-aligned)
  __shared__ _Float16 Vt[64][72];        // V tile T [dv][k]
  __shared__ _Float16 Pt[128][72];       // P tile   [q][k]

  const int q0   = qt * 128;
  const int qfr  = q0 + w * 16 + fr;     // A-frag q-row
  const int qcd0 = q0 + w * 16 + g * 4;  // C/D base q-row (regs r=0..3)

  // ---- zero-fill fully-masked attn tail (independent, fire early) ----
  {
    const int row = t >> 2;              // 0..127
    const int c0  = (t & 3) << 4;
    float* ap = attn + ((size_t)(b * HH + h) * QQ + q0 + row) * KK_ + c0;
    const float4 z = make_float4(0.f, 0.f, 0.f, 0.f);
    for (int k0 = ntv * 64; k0 < KK_; k0 += 64) {
      float4* d = (float4*)(ap + k0);
      d[0] = z; d[1] = z; d[2] = z; d[3] = z;
    }
  }

  // ---- Q fragments in registers, pre-scaled by 1/8 (exact pow2) ----
  f16x8 aq[2];
  {
    const float* qp = qs + ((size_t)(b * QQ + qfr) * HH + h) * DD + g * 8;
#pragma unroll
    for (int kk = 0; kk < 2; ++kk) {
      const float4 f0 = *(const float4*)(qp + kk * 32);
      const float4 f1 = *(const float4*)(qp + kk * 32 + 4);
      f16x8 v;
      v[0] = (_Float16)(f0.x * 0.125f); v[1] = (_Float16)(f0.y * 0.125f);
      v[2] = (_Float16)(f0.z * 0.125f); v[3] = (_Float16)(f0.w * 0.125f);
      v[4] = (_Float16)(f1.x * 0.125f); v[5] = (_Float16)(f1.y * 0.125f);
      v[6] = (_Float16)(f1.z * 0.125f); v[7] = (_Float16)(f1.w * 0.125f);
      aq[kk] = v;
    }
  }

  const float* biasr = bias + (size_t)qcd0 * KK_;
  float* attnr = attn + ((size_t)(b * HH + h) * QQ + qcd0) * KK_;

  // staging index precompute
  const int krow = t >> 2;               // t<256: K stage row
  const int kc0  = (t & 3) << 4;
  const int rho  = (t - 256) & 31;       // t>=256: V stage pair index
  const int dlt  = (t - 256) >> 5;       // 0..7

  // ================= PASS 1: running (m, l) =================
  float mrun[4], lrun[4];
#pragma unroll
  for (int r = 0; r < 4; ++r) { mrun[r] = -3e38f; lrun[r] = 0.f; }

  for (int k0 = 0; k0 < ntv * 64; k0 += 64) {
    if (t < 256) {
      const float* kp = ks + ((size_t)(b * KK_ + k0 + krow) * HH + h) * DD + kc0;
      const float4 a0 = ((const float4*)kp)[0], a1 = ((const float4*)kp)[1];
      const float4 a2 = ((const float4*)kp)[2], a3 = ((const float4*)kp)[3];
      f16x8 v0, v1;
      v0[0]=(_Float16)a0.x; v0[1]=(_Float16)a0.y; v0[2]=(_Float16)a0.z; v0[3]=(_Float16)a0.w;
      v0[4]=(_Float16)a1.x; v0[5]=(_Float16)a1.y; v0[6]=(_Float16)a1.z; v0[7]=(_Float16)a1.w;
      v1[0]=(_Float16)a2.x; v1[1]=(_Float16)a2.y; v1[2]=(_Float16)a2.z; v1[3]=(_Float16)a2.w;
      v1[4]=(_Float16)a3.x; v1[5]=(_Float16)a3.y; v1[6]=(_Float16)a3.z; v1[7]=(_Float16)a3.w;
      *(f16x8*)&Kl[krow][kc0]     = v0;
      *(f16x8*)&Kl[krow][kc0 + 8] = v1;
    }
    __syncthreads();

    float s[4][4];
#pragma unroll
    for (int c = 0; c < 4; ++c) {
      f32x4 acc = {0.f, 0.f, 0.f, 0.f};
      const int brow = c * 16 + fr;
#pragma unroll
      for (int kk = 0; kk < 2; ++kk) {
        const f16x8 bk = *(const f16x8*)&Kl[brow][kk * 32 + g * 8];
        acc = __builtin_amdgcn_mfma_f32_16x16x32_f16(aq[kk], bk, acc, 0, 0, 0);
      }
      const int col = k0 + c * 16 + fr;
      const bool msk = (col >= vl);
#pragma unroll
      for (int r = 0; r < 4; ++r) {
        const float sv = acc[r] + biasr[(size_t)r * KK_ + col];
        s[c][r] = msk ? NEG_INF_F : sv;
      }
    }
    __syncthreads();   // Kl reads done before next stage

    float mt[4];
#pragma unroll
    for (int r = 0; r < 4; ++r)
      mt[r] = fmaxf(fmaxf(s[0][r], s[1][r]), fmaxf(s[2][r], s[3][r]));
#pragma unroll
    for (int off = 1; off < 16; off <<= 1) {
#pragma unroll
      for (int r = 0; r < 4; ++r) mt[r] = fmaxf(mt[r], __shfl_xor(mt[r], off));
    }
    float lt[4] = {0.f, 0.f, 0.f, 0.f};
#pragma unroll
    for (int c = 0; c < 4; ++c)
#pragma unroll
      for (int r = 0; r < 4; ++r) lt[r] += __expf(s[c][r] - mt[r]);
#pragma unroll
    for (int off = 1; off < 16; off <<= 1) {
#pragma unroll
      for (int r = 0; r < 4; ++r) lt[r] += __shfl_xor(lt[r], off);
    }
#pragma unroll
    for (int r = 0; r < 4; ++r) {
      const float mn = fmaxf(mrun[r], mt[r]);
      lrun[r] = lrun[r] * __expf(mrun[r] - mn) + lt[r] * __expf(mt[r] - mn);
      mrun[r] = mn;
    }
  }

  float il[4];
#pragma unroll
  for (int r = 0; r < 4; ++r) il[r] = 1.f / lrun[r];

  // ================= PASS 2: attn write + PV =================
  f32x4 accv[4];
#pragma unroll
  for (int n = 0; n < 4; ++n) accv[n] = (f32x4){0.f, 0.f, 0.f, 0.f};

  for (int k0 = 0; k0 < ntv * 64; k0 += 64) {
    if (t < 256) {
      const float* kp = ks + ((size_t)(b * KK_ + k0 + krow) * HH + h) * DD + kc0;
      const float4 a0 = ((const float4*)kp)[0], a1 = ((const float4*)kp)[1];
      const float4 a2 = ((const float4*)kp)[2], a3 = ((const float4*)kp)[3];
      f16x8 v0, v1;
      v0[0]=(_Float16)a0.x; v0[1]=(_Float16)a0.y; v0[2]=(_Float16)a0.z; v0[3]=(_Float16)a0.w;
      v0[4]=(_Float16)a1.x; v0[5]=(_Float16)a1.y; v0[6]=(_Float16)a1.z; v0[7]=(_Float16)a1.w;
      v1[0]=(_Float16)a2.x; v1[1]=(_Float16)a2.y; v1[2]=(_Float16)a2.z; v1[3]=(_Float16)a2.w;
      v1[4]=(_Float16)a3.x; v1[5]=(_Float16)a3.y; v1[6]=(_Float16)a3.z; v1[7]=(_Float16)a3.w;
      *(f16x8*)&Kl[krow][kc0]     = v0;
      *(f16x8*)&Kl[krow][kc0 + 8] = v1;
    } else {
      // V^T staging: packed (k, k+1) pairs -> conflict-free b32 writes
      const float* vp = vs + ((size_t)(b * KK_ + k0 + 2 * rho) * HH + h) * DVV + dlt * 8;
      const float4 a0 = *(const float4*)(vp);
      const float4 a1 = *(const float4*)(vp + 4);
      const float4 b0 = *(const float4*)(vp + HH * DVV);
      const float4 b1 = *(const float4*)(vp + HH * DVV + 4);
      const float r0[8] = {a0.x, a0.y, a0.z, a0.w, a1.x, a1.y, a1.z, a1.w};
      const float r1[8] = {b0.x, b0.y, b0.z, b0.w, b1.x, b1.y, b1.z, b1.w};
#pragma unroll
      for (int i = 0; i < 8; ++i) {
        f16x2 pk;
        pk[0] = (_Float16)r0[i];
        pk[1] = (_Float16)r1[i];
        *(f16x2*)&Vt[dlt * 8 + i][2 * rho] = pk;
      }
    }
    __syncthreads();

    float p[4][4];
#pragma unroll
    for (int c = 0; c < 4; ++c) {
      f32x4 acc = {0.f, 0.f, 0.f, 0.f};
      const int brow = c * 16 + fr;
#pragma unroll
      for (int kk = 0; kk < 2; ++kk) {
        const f16x8 bk = *(const f16x8*)&Kl[brow][kk * 32 + g * 8];
        acc = __builtin_amdgcn_mfma_f32_16x16x32_f16(aq[kk], bk, acc, 0, 0, 0);
      }
      const int col = k0 + c * 16 + fr;
      const bool msk = (col >= vl);
#pragma unroll
      for (int r = 0; r < 4; ++r) {
        const float sv = msk ? NEG_INF_F : (acc[r] + biasr[(size_t)r * KK_ + col]);
        p[c][r] = __expf(sv - mrun[r]) * il[r];
      }
    }

    // write attn (fp32) + stage P (fp16) for PV
#pragma unroll
    for (int c = 0; c < 4; ++c) {
      const int col = k0 + c * 16 + fr;
#pragma unroll
      for (int r = 0; r < 4; ++r) {
        attnr[(size_t)r * KK_ + col] = p[c][r];
        Pt[w * 16 + g * 4 + r][c * 16 + fr] = (_Float16)p[c][r];
      }
    }

    // same-wave LDS RAW: drain DS queue before frag reads (rule #18)
    asm volatile("s_waitcnt lgkmcnt(0)" ::: "memory");
    __builtin_amdgcn_sched_barrier(0);

#pragma unroll
    for (int kk = 0; kk < 2; ++kk) {
      const f16x8 av = *(const f16x8*)&Pt[w * 16 + fr][kk * 32 + g * 8];
#pragma unroll
      for (int n = 0; n < 4; ++n) {
        const f16x8 bv = *(const f16x8*)&Vt[n * 16 + fr][kk * 32 + g * 8];
        accv[n] = __builtin_amdgcn_mfma_f32_16x16x32_f16(av, bv, accv[n], 0, 0, 0);
      }
    }
    __syncthreads();   // Kl/Vt reads done before next stage
  }

  // ---- write ctx: C/D col = dv (n*16+fr), row = q (g*4+r) ----
#pragma unroll
  for (int n = 0; n < 4; ++n) {
#pragma unroll
    for (int r = 0; r < 4; ++r) {
      const size_t o = ((size_t)(b * QQ + qcd0 + r) * HH + h) * DVV + n * 16 + fr;
      ctx[o] = accv[n][r];
    }
  }
}

// ---------------------------------------------------------------------------
extern "C" void kernel_launch(void* const* d_in, const int* in_sizes, int n_in,
                              void* d_out, int out_size, void* d_ws, size_t ws_size,
                              hipStream_t stream) {
  (void)in_sizes; (void)n_in; (void)d_ws; (void)ws_size; (void)out_size;
  const float* qs   = (const float*)d_in[0];
  const float* ks   = (const float*)d_in[1];
  const float* vs   = (const float*)d_in[2];
  const float* bias = (const float*)d_in[3];
  const int*   vlen = (const int*)d_in[4];
  float* out = (float*)d_out;

  fused_attn<<<dim3(512), dim3(512), 0, stream>>>(qs, ks, vs, bias, vlen, out);
}